// Round 5
// baseline (200.401 us; speedup 1.0000x reference)
//
#include <hip/hip_runtime.h>
#include <stdint.h>

// Problem constants
#define B_   2
#define S_   2048
#define D_   768
#define H_   12
#define DH_  64
#define N3_  2304   // 3*D
#define M_   4096   // B*S

typedef __attribute__((ext_vector_type(8))) short   bf16x8;
typedef __attribute__((ext_vector_type(4))) float   f32x4;
typedef __attribute__((ext_vector_type(4))) int     i32x4;
typedef __attribute__((ext_vector_type(4))) unsigned short u16x4;

// fold 1/sqrt(dh) * log2(e) into K at write time -> scores exit MFMA in exp2 domain
#define KSCALE 0.18033688011112042f

__device__ inline unsigned short f2bf(float f) {
    union { float f; unsigned u; } v; v.f = f;
    unsigned r = v.u + 0x7FFFu + ((v.u >> 16) & 1u);   // RNE
    return (unsigned short)(r >> 16);
}

// async 16B global -> LDS (DMA; LDS dest = wave-uniform base + lane*16)
__device__ inline void async_copy16(const void* g, void* l) {
    __builtin_amdgcn_global_load_lds((const __attribute__((address_space(1))) void*)g,
                                     (__attribute__((address_space(3))) void*)l, 16, 0, 0);
}

// ---------------------------------------------------------------------------
// Prep: fp32 -> bf16 elementwise (vectorized x4)
__global__ void cvt_bf16(const float* __restrict__ in, unsigned short* __restrict__ out, int n4) {
    int i = blockIdx.x * blockDim.x + threadIdx.x;
    if (i >= n4) return;
    f32x4 v = *(const f32x4*)(in + (size_t)i * 4);
    u16x4 o;
    o.x = f2bf(v.x); o.y = f2bf(v.y); o.z = f2bf(v.z); o.w = f2bf(v.w);
    *(u16x4*)(out + (size_t)i * 4) = o;
}

// Prep: tiled transpose fp32 [R][C] -> bf16 [C][R]; R,C multiples of 32.
__global__ void transpose_bf16(const float* __restrict__ in, unsigned short* __restrict__ out,
                               int R, int C) {
    __shared__ unsigned short t[32][33];
    int c0 = blockIdx.x * 32, r0 = blockIdx.y * 32;
    int tx = threadIdx.x, ty = threadIdx.y;
#pragma unroll
    for (int j = 0; j < 4; j++)
        t[ty + j * 8][tx] = f2bf(in[(size_t)(r0 + ty + j * 8) * C + c0 + tx]);
    __syncthreads();
#pragma unroll
    for (int j = 0; j < 4; j++)
        out[(size_t)(c0 + ty + j * 8) * R + r0 + tx] = t[tx][ty + j * 8];
}

// ---------------------------------------------------------------------------
// bf16 MFMA GEMM: C[M][N] = A[M][K] * Bt[N][K]^T + bias
// m97-style: global_load_lds width-16 staging, unpadded stride-32 LDS,
// 2-barrier K-loop. 128x128 tile, BK=32, 256 threads (4 waves 2x2).
template <int MODE>
__global__ __launch_bounds__(256) void gemm_bf16(
    const unsigned short* __restrict__ A,
    const unsigned short* __restrict__ Bt,
    const float* __restrict__ bias,
    void* __restrict__ Cout,
    int M, int N, int K)
{
    __shared__ __align__(16) short Al[128 * 32];
    __shared__ __align__(16) short Bl[128 * 32];

    const int tid  = threadIdx.x;
    const int w    = tid >> 6;
    const int lane = tid & 63;
    const int r    = lane & 15;
    const int quad = lane >> 4;
    const int m0   = blockIdx.y * 128;
    const int n0   = blockIdx.x * 128;
    const int wm   = (w & 1) * 64;
    const int wn   = (w >> 1) * 64;

    f32x4 acc[4][4];
#pragma unroll
    for (int i = 0; i < 4; i++)
#pragma unroll
        for (int j = 0; j < 4; j++) acc[i][j] = f32x4{0.f, 0.f, 0.f, 0.f};

    // staging: chunk c = p*256 + tid -> global row = c>>2, 16B-chunk cc = c&3;
    // LDS linear: chunk c at short-offset c*8 (row-major stride 32, unpadded).
    const int c0 = tid, c1 = tid + 256;
    const size_t ga0 = (size_t)(m0 + (c0 >> 2)) * K + (c0 & 3) * 8;
    const size_t ga1 = (size_t)(m0 + (c1 >> 2)) * K + (c1 & 3) * 8;
    const size_t gb0 = (size_t)(n0 + (c0 >> 2)) * K + (c0 & 3) * 8;
    const size_t gb1 = (size_t)(n0 + (c1 >> 2)) * K + (c1 & 3) * 8;
    short* lA0 = &Al[(0 * 256 + w * 64) * 8];   // wave-uniform bases
    short* lA1 = &Al[(1 * 256 + w * 64) * 8];
    short* lB0 = &Bl[(0 * 256 + w * 64) * 8];
    short* lB1 = &Bl[(1 * 256 + w * 64) * 8];

    for (int k0 = 0; k0 < K; k0 += 32) {
        __syncthreads();   // prev-iter LDS reads done before DMA overwrites
        async_copy16(A  + ga0 + k0, lA0);
        async_copy16(A  + ga1 + k0, lA1);
        async_copy16(Bt + gb0 + k0, lB0);
        async_copy16(Bt + gb1 + k0, lB1);
        __syncthreads();   // vmcnt(0) drain -> tiles resident

        bf16x8 af[4], bf[4];
#pragma unroll
        for (int mi = 0; mi < 4; mi++)
            af[mi] = *(const bf16x8*)&Al[(wm + mi * 16 + r) * 32 + quad * 8];
#pragma unroll
        for (int ni = 0; ni < 4; ni++)
            bf[ni] = *(const bf16x8*)&Bl[(wn + ni * 16 + r) * 32 + quad * 8];
#pragma unroll
        for (int mi = 0; mi < 4; mi++)
#pragma unroll
            for (int ni = 0; ni < 4; ni++)
                acc[mi][ni] = __builtin_amdgcn_mfma_f32_16x16x32_bf16(
                    af[mi], bf[ni], acc[mi][ni], 0, 0, 0);
    }

    // Epilogue. C/D layout: col = lane&15 (+16*ni), row = quad*4 + reg (+16*mi)
    if (MODE == 0) {
        unsigned short* Q = (unsigned short*)Cout;   // Q,K,V^T consecutive
        const size_t one = (size_t)B_ * H_ * S_ * DH_;
#pragma unroll
        for (int ni = 0; ni < 4; ni++) {
            int col  = n0 + wn + ni * 16 + r;        // 0..2303
            float bv = bias[col];
            int part = col / 768;                    // 0=q 1=k 2=v
            int cc   = col - part * 768;
            int h    = cc >> 6;
            int d    = cc & 63;
            float scl = (part == 1) ? KSCALE : 1.0f;
            unsigned short* dst = Q + (size_t)part * one;
#pragma unroll
            for (int mi = 0; mi < 4; mi++) {
#pragma unroll
                for (int i = 0; i < 4; i++) {
                    int row = m0 + wm + mi * 16 + quad * 4 + i;  // = b*S + s
                    int b   = row >> 11;
                    int s   = row & 2047;
                    float v = (acc[mi][ni][i] + bv) * scl;
                    if (part < 2)
                        dst[(((size_t)(b * H_ + h)) * S_ + s) * DH_ + d] = f2bf(v);
                    else  // V stored transposed: [B*H][dh][S]
                        dst[(((size_t)(b * H_ + h)) * DH_ + d) * S_ + s] = f2bf(v);
                }
            }
        }
    } else {
        float* Cf = (float*)Cout;
#pragma unroll
        for (int ni = 0; ni < 4; ni++) {
            int col  = n0 + wn + ni * 16 + r;
            float bv = bias[col];
#pragma unroll
            for (int mi = 0; mi < 4; mi++) {
#pragma unroll
                for (int i = 0; i < 4; i++) {
                    int row = m0 + wm + mi * 16 + quad * 4 + i;
                    Cf[(size_t)row * N + col] = acc[mi][ni][i] + bv;
                }
            }
        }
    }
}

// ---------------------------------------------------------------------------
// Flash attention v3: 2 waves x 32 q-rows (B-frag reads amortized 2x),
// unpadded stride-64 LDS tiles with XOR chunk swizzle (conflict-free frag reads),
// register-prefetch staging pipeline. Grid = 768 blocks x 128 threads.
// Q,K: bf16 [B*H][S][64] (K pre-scaled by KSCALE). Vt: bf16 [B*H][64][S].
__global__ __launch_bounds__(128) void attn_kernel(
    const unsigned short* __restrict__ Q,
    const unsigned short* __restrict__ K,
    const unsigned short* __restrict__ Vt,
    unsigned short* __restrict__ Out)
{
    __shared__ __align__(16) short Kl[64 * 64];      // [key][dh], chunk^=(row&7)
    __shared__ __align__(16) short Vl[64 * 64];      // [dh][key], chunk^=(row&7)
    __shared__ __align__(16) short Pl[2][32 * 64];   // per-wave [q][key], chunk^=(row&7)

    const int tid  = threadIdx.x;
    const int w    = tid >> 6;
    const int lane = tid & 63;
    const int r    = lane & 15;
    const int quad = lane >> 4;
    const int xk   = r & 7;               // XOR key for fragment reads (row&7 == r&7)
    const int bid  = blockIdx.x;
    const int bh   = bid % 24;            // head-major -> XCD L2 locality
    const int qb   = bid / 24;
    const int b    = bh / H_;
    const int h    = bh - b * H_;
    const size_t baseQK = (size_t)bh * S_ * DH_;
    const size_t baseV  = (size_t)bh * DH_ * S_;
    const int q0   = qb * 64;

    // Q fragments: 2 mi-blocks x 2 k-halves (A[m=r][k=quad*8+j])
    bf16x8 qf[2][2];
#pragma unroll
    for (int mi = 0; mi < 2; mi++) {
        const unsigned short* qp =
            Q + baseQK + (size_t)(q0 + w * 32 + mi * 16 + r) * DH_ + quad * 8;
        qf[mi][0] = *(const bf16x8*)(qp);
        qf[mi][1] = *(const bf16x8*)(qp + 32);
    }

    f32x4 o[2][4];
#pragma unroll
    for (int mi = 0; mi < 2; mi++)
#pragma unroll
        for (int nb = 0; nb < 4; nb++) o[mi][nb] = f32x4{0.f, 0.f, 0.f, 0.f};
    float lsum[2][4] = {{0.f, 0.f, 0.f, 0.f}, {0.f, 0.f, 0.f, 0.f}};

    // staging: chunk cid = p*128 + tid (p=0..3); srow = cid>>3, schk = cid&7
    // K tile contiguous in global; V rows are S_-strided.
    const int srow_l = tid >> 3, schk = tid & 7;
    const int lbase  = srow_l * 64 + (schk ^ (srow_l & 7)) * 8;   // + p*1024
    const unsigned short* kg = K  + baseQK + tid * 8;                      // + p*1024 + kt*4096
    const unsigned short* vg = Vt + baseV + (size_t)srow_l * S_ + schk * 8; // + p*16*S_ + kt*64
    short* pl = &Pl[w][0];

    i32x4 kreg[4], vreg[4];
#pragma unroll
    for (int p = 0; p < 4; p++) {
        kreg[p] = *(const i32x4*)(kg + p * 1024);
        vreg[p] = *(const i32x4*)(vg + (size_t)p * 16 * S_);
    }

    for (int kt = 0; kt < 32; kt++) {
        __syncthreads();
#pragma unroll
        for (int p = 0; p < 4; p++) {
            *(i32x4*)&Kl[p * 1024 + lbase] = kreg[p];
            *(i32x4*)&Vl[p * 1024 + lbase] = vreg[p];
        }
        __syncthreads();

        if (kt != 31) {
            const unsigned short* kn = kg + (kt + 1) * 4096;
            const unsigned short* vn = vg + (kt + 1) * 64;
#pragma unroll
            for (int p = 0; p < 4; p++) {
                kreg[p] = *(const i32x4*)(kn + p * 1024);
                vreg[p] = *(const i32x4*)(vn + (size_t)p * 16 * S_);
            }
        }

        // scores S = Q K^T (exp2 domain; KSCALE folded into K)
        f32x4 sa[2][4];
#pragma unroll
        for (int mi = 0; mi < 2; mi++)
#pragma unroll
            for (int nb = 0; nb < 4; nb++) sa[mi][nb] = f32x4{0.f, 0.f, 0.f, 0.f};
#pragma unroll
        for (int t = 0; t < 2; t++)
#pragma unroll
            for (int nb = 0; nb < 4; nb++) {
                bf16x8 kf = *(const bf16x8*)&Kl[(nb * 16 + r) * 64 + ((t * 4 + quad) ^ xk) * 8];
#pragma unroll
                for (int mi = 0; mi < 2; mi++)
                    sa[mi][nb] = __builtin_amdgcn_mfma_f32_16x16x32_bf16(
                        qf[mi][t], kf, sa[mi][nb], 0, 0, 0);
            }

        // p = exp2(s); per-lane row sums; park P in LDS (C-layout -> A-layout)
#pragma unroll
        for (int mi = 0; mi < 2; mi++)
#pragma unroll
            for (int nb = 0; nb < 4; nb++)
#pragma unroll
                for (int i = 0; i < 4; i++) {
                    float p = __builtin_amdgcn_exp2f(sa[mi][nb][i]);
                    lsum[mi][i] += p;
                    int prow = quad * 4 + i;
                    int pch  = (nb * 2 + (r >> 3)) ^ (prow & 7);
                    pl[(mi * 16 + prow) * 64 + pch * 8 + (r & 7)] = (short)f2bf(p);
                }

        bf16x8 ap[2][2];
#pragma unroll
        for (int mi = 0; mi < 2; mi++)
#pragma unroll
            for (int kf2 = 0; kf2 < 2; kf2++)
                ap[mi][kf2] = *(const bf16x8*)&pl[(mi * 16 + r) * 64 +
                                                  (((kf2 * 4 + quad) ^ xk)) * 8];
#pragma unroll
        for (int nb = 0; nb < 4; nb++) {
#pragma unroll
            for (int kf2 = 0; kf2 < 2; kf2++) {
                bf16x8 vf = *(const bf16x8*)&Vl[(nb * 16 + r) * 64 +
                                                (((kf2 * 4 + quad) ^ xk)) * 8];
#pragma unroll
                for (int mi = 0; mi < 2; mi++)
                    o[mi][nb] = __builtin_amdgcn_mfma_f32_16x16x32_bf16(
                        ap[mi][kf2], vf, o[mi][nb], 0, 0, 0);
            }
        }
    }

    // epilogue: reduce l across the 16 column-lanes, normalize, store
#pragma unroll
    for (int mi = 0; mi < 2; mi++)
#pragma unroll
        for (int i = 0; i < 4; i++) {
            float l = lsum[mi][i];
            l += __shfl_xor(l, 1);
            l += __shfl_xor(l, 2);
            l += __shfl_xor(l, 4);
            l += __shfl_xor(l, 8);
            float inv = 1.0f / l;
            int s = q0 + w * 32 + mi * 16 + quad * 4 + i;
            size_t ob = ((size_t)b * S_ + s) * D_ + h * DH_;
#pragma unroll
            for (int nb = 0; nb < 4; nb++)
                Out[ob + nb * 16 + r] = f2bf(o[mi][nb][i] * inv);
        }
}

// ---------------------------------------------------------------------------
extern "C" void kernel_launch(void* const* d_in, const int* in_sizes, int n_in,
                              void* d_out, int out_size, void* d_ws, size_t ws_size,
                              hipStream_t stream) {
    const float* x     = (const float*)d_in[0];
    const float* w_in  = (const float*)d_in[1];
    const float* b_in  = (const float*)d_in[2];
    const float* w_out = (const float*)d_in[3];
    const float* b_out = (const float*)d_in[4];
    float* out = (float*)d_out;
    char* ws = (char*)d_ws;

    // workspace layout (bytes)
    unsigned short* xb    = (unsigned short*)(ws);              // 4096x768 bf16
    unsigned short* winT  = (unsigned short*)(ws + 6291456);    // 2304x768 bf16
    unsigned short* woutT = (unsigned short*)(ws + 9830400);    // 768x768 bf16
    unsigned short* QKV   = (unsigned short*)(ws + 11010048);   // Q,K [24][2048][64] + Vt [24][64][2048]
    unsigned short* attn  = (unsigned short*)(ws + 29884416);   // 4096x768 bf16

    const size_t one = (size_t)B_ * H_ * S_ * DH_;

    cvt_bf16<<<3072, 256, 0, stream>>>(x, xb, (M_ * D_) / 4);
    transpose_bf16<<<dim3(N3_ / 32, D_ / 32), dim3(32, 8), 0, stream>>>(w_in, winT, D_, N3_);
    transpose_bf16<<<dim3(D_ / 32, D_ / 32), dim3(32, 8), 0, stream>>>(w_out, woutT, D_, D_);

    gemm_bf16<0><<<dim3(N3_ / 128, M_ / 128), 256, 0, stream>>>(
        xb, winT, b_in, (void*)QKV, M_, N3_, D_);

    attn_kernel<<<B_ * H_ * (S_ / 64), 128, 0, stream>>>(
        QKV, QKV + one, QKV + 2 * one, attn);

    gemm_bf16<1><<<dim3(D_ / 128, M_ / 128), 256, 0, stream>>>(
        attn, woutT, b_out, (void*)out, M_, D_, D_);
}

// Round 6
// 183.363 us; speedup vs baseline: 1.0929x; 1.0929x over previous
//
#include <hip/hip_runtime.h>
#include <stdint.h>

// Problem constants
#define B_   2
#define S_   2048
#define D_   768
#define H_   12
#define DH_  64
#define N3_  2304   // 3*D
#define M_   4096   // B*S

typedef __attribute__((ext_vector_type(8))) short   bf16x8;
typedef __attribute__((ext_vector_type(4))) float   f32x4;
typedef __attribute__((ext_vector_type(4))) int     i32x4;
typedef __attribute__((ext_vector_type(4))) unsigned short u16x4;

// fold 1/sqrt(dh) * log2(e) into K at write time -> scores exit MFMA in exp2 domain
#define KSCALE 0.18033688011112042f

__device__ inline unsigned short f2bf(float f) {
    union { float f; unsigned u; } v; v.f = f;
    unsigned r = v.u + 0x7FFFu + ((v.u >> 16) & 1u);   // RNE
    return (unsigned short)(r >> 16);
}

// async 16B global -> LDS (DMA; LDS dest = wave-uniform base + lane*16)
__device__ inline void async_copy16(const void* g, void* l) {
    __builtin_amdgcn_global_load_lds((const __attribute__((address_space(1))) void*)g,
                                     (__attribute__((address_space(3))) void*)l, 16, 0, 0);
}

// ---------------------------------------------------------------------------
// Prep: fp32 -> bf16 elementwise (vectorized x4)
__global__ void cvt_bf16(const float* __restrict__ in, unsigned short* __restrict__ out, int n4) {
    int i = blockIdx.x * blockDim.x + threadIdx.x;
    if (i >= n4) return;
    f32x4 v = *(const f32x4*)(in + (size_t)i * 4);
    u16x4 o;
    o.x = f2bf(v.x); o.y = f2bf(v.y); o.z = f2bf(v.z); o.w = f2bf(v.w);
    *(u16x4*)(out + (size_t)i * 4) = o;
}

// Prep: tiled transpose fp32 [R][C] -> bf16 [C][R]; R,C multiples of 32.
__global__ void transpose_bf16(const float* __restrict__ in, unsigned short* __restrict__ out,
                               int R, int C) {
    __shared__ unsigned short t[32][33];
    int c0 = blockIdx.x * 32, r0 = blockIdx.y * 32;
    int tx = threadIdx.x, ty = threadIdx.y;
#pragma unroll
    for (int j = 0; j < 4; j++)
        t[ty + j * 8][tx] = f2bf(in[(size_t)(r0 + ty + j * 8) * C + c0 + tx]);
    __syncthreads();
#pragma unroll
    for (int j = 0; j < 4; j++)
        out[(size_t)(c0 + ty + j * 8) * R + r0 + tx] = t[tx][ty + j * 8];
}

// V [bh][s][64] bf16 -> Vt [bh][64][s] bf16.  64x64 tiles, coalesced both sides.
// grid = 24*32 blocks x 256 thr.
__global__ void vtrans(const unsigned short* __restrict__ V, unsigned short* __restrict__ Vt) {
    __shared__ unsigned short t[64 * 65];
    const int bid = blockIdx.x;
    const int bh  = bid >> 5;
    const int s0  = (bid & 31) * 64;
    const int tid = threadIdx.x;
    const unsigned short* src = V  + (size_t)bh * S_ * DH_ + (size_t)s0 * DH_;
    unsigned short*       dst = Vt + (size_t)bh * DH_ * S_ + s0;
#pragma unroll
    for (int p = 0; p < 2; p++) {
        int c = p * 256 + tid;          // 0..511
        int s = c >> 3, dc = c & 7;
        i32x4 v = *(const i32x4*)&src[s * 64 + dc * 8];
        const unsigned short* e = (const unsigned short*)&v;
#pragma unroll
        for (int j = 0; j < 8; j++) t[(dc * 8 + j) * 65 + s] = e[j];
    }
    __syncthreads();
#pragma unroll
    for (int p = 0; p < 2; p++) {
        int c = p * 256 + tid;
        int d = c >> 3, sc = c & 7;
        unsigned short tmp[8];
#pragma unroll
        for (int j = 0; j < 8; j++) tmp[j] = t[d * 65 + sc * 8 + j];
        *(i32x4*)&dst[(size_t)d * S_ + sc * 8] = *(const i32x4*)tmp;
    }
}

// ---------------------------------------------------------------------------
// bf16 MFMA GEMM: C[M][N] = A[M][K] * Bt[N][K]^T + bias
// m97-style: global_load_lds width-16 staging, unpadded stride-32 LDS,
// 2-barrier K-loop. 128x128 tile, BK=32, 256 threads (4 waves 2x2).
// MODE 0: scatter bf16 into Q/K (Cout, natural [bh][s][dh], K scaled by KSCALE)
//         and V natural [bh][s][dh] into Vnat (coalesced; Vt made separately).
// MODE 1: fp32 C row-major to Cout.
template <int MODE>
__global__ __launch_bounds__(256) void gemm_bf16(
    const unsigned short* __restrict__ A,
    const unsigned short* __restrict__ Bt,
    const float* __restrict__ bias,
    void* __restrict__ Cout,
    unsigned short* __restrict__ Vnat,
    int M, int N, int K)
{
    __shared__ __align__(16) short Al[128 * 32];
    __shared__ __align__(16) short Bl[128 * 32];

    const int tid  = threadIdx.x;
    const int w    = tid >> 6;
    const int lane = tid & 63;
    const int r    = lane & 15;
    const int quad = lane >> 4;
    const int m0   = blockIdx.y * 128;
    const int n0   = blockIdx.x * 128;
    const int wm   = (w & 1) * 64;
    const int wn   = (w >> 1) * 64;

    f32x4 acc[4][4];
#pragma unroll
    for (int i = 0; i < 4; i++)
#pragma unroll
        for (int j = 0; j < 4; j++) acc[i][j] = f32x4{0.f, 0.f, 0.f, 0.f};

    // staging: chunk c = p*256 + tid -> global row = c>>2, 16B-chunk cc = c&3;
    // LDS linear: chunk c at short-offset c*8 (row-major stride 32, unpadded).
    const int c0 = tid, c1 = tid + 256;
    const size_t ga0 = (size_t)(m0 + (c0 >> 2)) * K + (c0 & 3) * 8;
    const size_t ga1 = (size_t)(m0 + (c1 >> 2)) * K + (c1 & 3) * 8;
    const size_t gb0 = (size_t)(n0 + (c0 >> 2)) * K + (c0 & 3) * 8;
    const size_t gb1 = (size_t)(n0 + (c1 >> 2)) * K + (c1 & 3) * 8;
    short* lA0 = &Al[(0 * 256 + w * 64) * 8];   // wave-uniform bases
    short* lA1 = &Al[(1 * 256 + w * 64) * 8];
    short* lB0 = &Bl[(0 * 256 + w * 64) * 8];
    short* lB1 = &Bl[(1 * 256 + w * 64) * 8];

    for (int k0 = 0; k0 < K; k0 += 32) {
        __syncthreads();   // prev-iter LDS reads done before DMA overwrites
        async_copy16(A  + ga0 + k0, lA0);
        async_copy16(A  + ga1 + k0, lA1);
        async_copy16(Bt + gb0 + k0, lB0);
        async_copy16(Bt + gb1 + k0, lB1);
        __syncthreads();   // vmcnt(0) drain -> tiles resident

        bf16x8 af[4], bf[4];
#pragma unroll
        for (int mi = 0; mi < 4; mi++)
            af[mi] = *(const bf16x8*)&Al[(wm + mi * 16 + r) * 32 + quad * 8];
#pragma unroll
        for (int ni = 0; ni < 4; ni++)
            bf[ni] = *(const bf16x8*)&Bl[(wn + ni * 16 + r) * 32 + quad * 8];
#pragma unroll
        for (int mi = 0; mi < 4; mi++)
#pragma unroll
            for (int ni = 0; ni < 4; ni++)
                acc[mi][ni] = __builtin_amdgcn_mfma_f32_16x16x32_bf16(
                    af[mi], bf[ni], acc[mi][ni], 0, 0, 0);
    }

    // Epilogue. C/D layout: col = lane&15 (+16*ni), row = quad*4 + reg (+16*mi)
    if (MODE == 0) {
        unsigned short* Q = (unsigned short*)Cout;   // Q,K consecutive
        const size_t one = (size_t)B_ * H_ * S_ * DH_;
#pragma unroll
        for (int ni = 0; ni < 4; ni++) {
            int col  = n0 + wn + ni * 16 + r;        // 0..2303
            float bv = bias[col];
            int part = col / 768;                    // 0=q 1=k 2=v
            int cc   = col - part * 768;
            int h    = cc >> 6;
            int d    = cc & 63;
            float scl = (part == 1) ? KSCALE : 1.0f;
            unsigned short* dst = (part == 2) ? Vnat : (Q + (size_t)part * one);
#pragma unroll
            for (int mi = 0; mi < 4; mi++) {
#pragma unroll
                for (int i = 0; i < 4; i++) {
                    int row = m0 + wm + mi * 16 + quad * 4 + i;  // = b*S + s
                    int b   = row >> 11;
                    int s   = row & 2047;
                    float v = (acc[mi][ni][i] + bv) * scl;
                    dst[(((size_t)(b * H_ + h)) * S_ + s) * DH_ + d] = f2bf(v);
                }
            }
        }
    } else {
        float* Cf = (float*)Cout;
#pragma unroll
        for (int ni = 0; ni < 4; ni++) {
            int col  = n0 + wn + ni * 16 + r;
            float bv = bias[col];
#pragma unroll
            for (int mi = 0; mi < 4; mi++) {
#pragma unroll
                for (int i = 0; i < 4; i++) {
                    int row = m0 + wm + mi * 16 + quad * 4 + i;
                    Cf[(size_t)row * N + col] = acc[mi][ni][i] + bv;
                }
            }
        }
    }
}

// ---------------------------------------------------------------------------
// Flash attention v4 = R4 structure (4 waves x 16 q-rows, 256 thr, grid 768,
// register-prefetch staging) + R5's zero-conflict swizzled LDS layout
// (unpadded stride 64, chunk ^= (row&7)).
// Q,K: bf16 [B*H][S][64] (K pre-scaled by KSCALE). Vt: bf16 [B*H][64][S].
__global__ __launch_bounds__(256) void attn_kernel(
    const unsigned short* __restrict__ Q,
    const unsigned short* __restrict__ K,
    const unsigned short* __restrict__ Vt,
    unsigned short* __restrict__ Out)
{
    __shared__ __align__(16) short Kl[64 * 64];      // [key][dh], chunk^=(row&7)
    __shared__ __align__(16) short Vl[64 * 64];      // [dh][key], chunk^=(row&7)
    __shared__ __align__(16) short Pl[4][16 * 64];   // per-wave [q][key], chunk^=(row&7)

    const int tid  = threadIdx.x;
    const int w    = tid >> 6;
    const int lane = tid & 63;
    const int r    = lane & 15;
    const int quad = lane >> 4;
    const int xk   = r & 7;               // XOR key for fragment reads (row&7 == r&7)
    const int bid  = blockIdx.x;
    const int bh   = bid % 24;            // head-major -> XCD L2 locality
    const int qb   = bid / 24;
    const int b    = bh / H_;
    const int h    = bh - b * H_;
    const size_t baseQK = (size_t)bh * S_ * DH_;
    const size_t baseV  = (size_t)bh * DH_ * S_;
    const int q0   = qb * 64;

    // Q fragments (A-operand: A[m=r][k=quad*8+j]) for this wave's 16 rows
    bf16x8 qf[2];
    {
        const unsigned short* qp = Q + baseQK + (size_t)(q0 + w * 16 + r) * DH_ + quad * 8;
        qf[0] = *(const bf16x8*)(qp);
        qf[1] = *(const bf16x8*)(qp + 32);
    }

    f32x4 o[4];
#pragma unroll
    for (int nb = 0; nb < 4; nb++) o[nb] = f32x4{0.f, 0.f, 0.f, 0.f};
    float lsum[4] = {0.f, 0.f, 0.f, 0.f};

    // staging: chunk c = p*256 + tid (p=0,1); srow = c>>3 (0..63), schk = c&7
    const int srw = tid >> 3, schk = tid & 7;          // rows 0..31 for p=0
    const unsigned short* kg = K  + baseQK + tid * 8;                       // p1: +2048
    const unsigned short* vg = Vt + baseV + (size_t)srw * S_ + schk * 8;    // p1: +32*S_
    const int lb = srw * 64 + (schk ^ (srw & 7)) * 8;                       // p1: +2048
    short* pl = &Pl[w][0];

    i32x4 kreg[2], vreg[2];
    kreg[0] = *(const i32x4*)(kg);
    kreg[1] = *(const i32x4*)(kg + 2048);
    vreg[0] = *(const i32x4*)(vg);
    vreg[1] = *(const i32x4*)(vg + 32 * S_);

    for (int kt = 0; kt < 32; kt++) {
        __syncthreads();
        *(i32x4*)&Kl[lb]        = kreg[0];
        *(i32x4*)&Kl[lb + 2048] = kreg[1];
        *(i32x4*)&Vl[lb]        = vreg[0];
        *(i32x4*)&Vl[lb + 2048] = vreg[1];
        __syncthreads();

        if (kt != 31) {
            const unsigned short* kn = kg + (kt + 1) * 4096;
            const unsigned short* vn = vg + (kt + 1) * 64;
            kreg[0] = *(const i32x4*)(kn);
            kreg[1] = *(const i32x4*)(kn + 2048);
            vreg[0] = *(const i32x4*)(vn);
            vreg[1] = *(const i32x4*)(vn + 32 * S_);
        }

        // scores S = Q K^T (exp2 domain; KSCALE folded into K)
        f32x4 sa[4];
#pragma unroll
        for (int nb = 0; nb < 4; nb++) sa[nb] = f32x4{0.f, 0.f, 0.f, 0.f};
#pragma unroll
        for (int t = 0; t < 2; t++)
#pragma unroll
            for (int nb = 0; nb < 4; nb++) {
                bf16x8 kf = *(const bf16x8*)&Kl[(nb * 16 + r) * 64 + ((t * 4 + quad) ^ xk) * 8];
                sa[nb] = __builtin_amdgcn_mfma_f32_16x16x32_bf16(qf[t], kf, sa[nb], 0, 0, 0);
            }

        // p = exp2(s); per-lane row sums; park P in LDS (C-layout -> A-layout)
#pragma unroll
        for (int nb = 0; nb < 4; nb++)
#pragma unroll
            for (int i = 0; i < 4; i++) {
                float p = __builtin_amdgcn_exp2f(sa[nb][i]);
                lsum[i] += p;
                int prow = quad * 4 + i;
                int pch  = (nb * 2 + (r >> 3)) ^ (prow & 7);
                pl[prow * 64 + pch * 8 + (r & 7)] = (short)f2bf(p);
            }

        bf16x8 ap0 = *(const bf16x8*)&pl[r * 64 + ((0 * 4 + quad) ^ xk) * 8];
        bf16x8 ap1 = *(const bf16x8*)&pl[r * 64 + ((1 * 4 + quad) ^ xk) * 8];
#pragma unroll
        for (int nb = 0; nb < 4; nb++) {
            bf16x8 v0 = *(const bf16x8*)&Vl[(nb * 16 + r) * 64 + ((0 * 4 + quad) ^ xk) * 8];
            bf16x8 v1 = *(const bf16x8*)&Vl[(nb * 16 + r) * 64 + ((1 * 4 + quad) ^ xk) * 8];
            o[nb] = __builtin_amdgcn_mfma_f32_16x16x32_bf16(ap0, v0, o[nb], 0, 0, 0);
            o[nb] = __builtin_amdgcn_mfma_f32_16x16x32_bf16(ap1, v1, o[nb], 0, 0, 0);
        }
    }

    // epilogue: reduce l across the 16 column-lanes, normalize, store
#pragma unroll
    for (int i = 0; i < 4; i++) {
        float l = lsum[i];
        l += __shfl_xor(l, 1);
        l += __shfl_xor(l, 2);
        l += __shfl_xor(l, 4);
        l += __shfl_xor(l, 8);
        float inv = 1.0f / l;
        int s = q0 + w * 16 + quad * 4 + i;
        size_t ob = ((size_t)b * S_ + s) * D_ + h * DH_;
#pragma unroll
        for (int nb = 0; nb < 4; nb++)
            Out[ob + nb * 16 + r] = f2bf(o[nb][i] * inv);
    }
}

// ---------------------------------------------------------------------------
extern "C" void kernel_launch(void* const* d_in, const int* in_sizes, int n_in,
                              void* d_out, int out_size, void* d_ws, size_t ws_size,
                              hipStream_t stream) {
    const float* x     = (const float*)d_in[0];
    const float* w_in  = (const float*)d_in[1];
    const float* b_in  = (const float*)d_in[2];
    const float* w_out = (const float*)d_in[3];
    const float* b_out = (const float*)d_in[4];
    float* out = (float*)d_out;
    char* ws = (char*)d_ws;

    // workspace layout (bytes), total 36.2 MB (same footprint as R1-R5):
    //   [0,        6291456)  xb (x bf16)            -> reused as attn output after gemm1
    //   [6291456,  9830400)  winT
    //   [9830400, 11010048)  woutT
    //   [11010048,29884416)  QKV: Q, K natural; slot 3 holds final Vt
    //   [29884416,36175872)  tmpV (V natural from gemm1; dead after vtrans)
    unsigned short* xb    = (unsigned short*)(ws);
    unsigned short* winT  = (unsigned short*)(ws + 6291456);
    unsigned short* woutT = (unsigned short*)(ws + 9830400);
    unsigned short* QKV   = (unsigned short*)(ws + 11010048);
    unsigned short* tmpV  = (unsigned short*)(ws + 29884416);

    const size_t one = (size_t)B_ * H_ * S_ * DH_;
    unsigned short* Vtbuf  = QKV + 2 * one;
    unsigned short* attnO  = xb;    // xb dead after gemm1

    cvt_bf16<<<3072, 256, 0, stream>>>(x, xb, (M_ * D_) / 4);
    transpose_bf16<<<dim3(N3_ / 32, D_ / 32), dim3(32, 8), 0, stream>>>(w_in, winT, D_, N3_);
    transpose_bf16<<<dim3(D_ / 32, D_ / 32), dim3(32, 8), 0, stream>>>(w_out, woutT, D_, D_);

    gemm_bf16<0><<<dim3(N3_ / 128, M_ / 128), 256, 0, stream>>>(
        xb, winT, b_in, (void*)QKV, tmpV, M_, N3_, D_);

    vtrans<<<24 * 32, 256, 0, stream>>>(tmpV, Vtbuf);

    attn_kernel<<<B_ * H_ * (S_ / 64), 256, 0, stream>>>(
        QKV, QKV + one, Vtbuf, attnO);

    gemm_bf16<1><<<dim3(D_ / 128, M_ / 128), 256, 0, stream>>>(
        attnO, woutT, b_out, (void*)out, nullptr, M_, D_, D_);
}